// Round 3
// baseline (401.286 us; speedup 1.0000x reference)
//
#include <hip/hip_runtime.h>
#include <math.h>

// Problem constants (from reference setup_inputs)
#define L_SEQ 1024
#define BATCH 64
#define HDIM  1024
#define WPB   4      // waves per block (256 threads)

#define LOG2E 1.44269504088896340736f

// ---------------------------------------------------------------------------
// Kernel 1: per-(batch, l-chunk) online-softmax partials (flash-decode style).
// One wave per (b, chunk). Lane j owns h = {4j, 256+4j, 512+4j, 768+4j}
// (float4-strided: one wave load instruction = 64 lanes x 16B = 1KB contig).
// Rows processed in groups of 2 with an explicit VGPR double-buffer: loads for
// group g+1 are issued before computing group g, so the memory pipe never
// idles during the dot/butterfly/exp serial chain. Running-max rescale is a
// wave-uniform branch (scores identical across lanes post-reduction), taken
// only ~log(chunk) times. Softmax in base-2 domain (exp2f -> v_exp_f32).
// Partial record r = b*SPLIT + k:
//   wsC[r*HDIM + h]      = sum_{l in chunk} 2^(s_l*log2e - m_r) * enc[l,b,h]
//   wsML[2r], wsML[2r+1] = (m_r, lsum_r)   (m in base-2 domain)
// ---------------------------------------------------------------------------
template <int SPLIT, int CHUNK>
__global__ __launch_bounds__(256, 4) void attn_partial_kernel(
    const float* __restrict__ enc, const float* __restrict__ dec,
    float* __restrict__ wsC, float* __restrict__ wsML)
{
    constexpr int NG = CHUNK / 2;           // groups of 2 rows
    const int tid  = threadIdx.x;
    const int lane = tid & 63;
    const int wave = tid >> 6;
    const int w    = blockIdx.x * WPB + wave;   // global wave id
    const int b    = w / SPLIT;
    const int k    = w - b * SPLIT;
    const int l0   = k * CHUNK;

    // This lane's slice of dec[b,:] (16 floats = 4 float4)
    const float4* decv = (const float4*)(dec + (size_t)b * HDIM);
    float4 d[4];
    #pragma unroll
    for (int q = 0; q < 4; ++q) d[q] = decv[lane + 64 * q];

    float m = -INFINITY;   // running max (base-2 domain)
    float lsum = 0.0f;
    float4 a[4];
    #pragma unroll
    for (int q = 0; q < 4; ++q) a[q] = make_float4(0.f, 0.f, 0.f, 0.f);

    const size_t row_stride = (size_t)BATCH * HDIM;  // floats from l to l+1
    const float* base0 = enc + ((size_t)l0 * BATCH + b) * HDIM;

    // Double-buffered staging: R[buf][row][q]
    float4 R[2][2][4];

    // Prime buffer 0 with group 0 (rows l0, l0+1)
    #pragma unroll
    for (int r = 0; r < 2; ++r) {
        const float4* row = (const float4*)(base0 + r * row_stride);
        #pragma unroll
        for (int q = 0; q < 4; ++q) R[0][r][q] = row[lane + 64 * q];
    }

    #pragma unroll
    for (int g = 0; g < NG; ++g) {
        const int buf = g & 1;

        // Issue next group's loads into the other buffer (prefetch)
        if (g + 1 < NG) {
            const float* nbase = base0 + (size_t)(2 * (g + 1)) * row_stride;
            #pragma unroll
            for (int r = 0; r < 2; ++r) {
                const float4* row = (const float4*)(nbase + r * row_stride);
                #pragma unroll
                for (int q = 0; q < 4; ++q) R[buf ^ 1][r][q] = row[lane + 64 * q];
            }
        }

        // Two per-lane partial dots on the current buffer
        float p0 = 0.0f, p1 = 0.0f;
        #pragma unroll
        for (int q = 0; q < 4; ++q) {
            p0 = fmaf(R[buf][0][q].x, d[q].x, p0);
            p0 = fmaf(R[buf][0][q].y, d[q].y, p0);
            p0 = fmaf(R[buf][0][q].z, d[q].z, p0);
            p0 = fmaf(R[buf][0][q].w, d[q].w, p0);
            p1 = fmaf(R[buf][1][q].x, d[q].x, p1);
            p1 = fmaf(R[buf][1][q].y, d[q].y, p1);
            p1 = fmaf(R[buf][1][q].z, d[q].z, p1);
            p1 = fmaf(R[buf][1][q].w, d[q].w, p1);
        }

        // Two concurrent wave64 butterfly reduces
        #pragma unroll
        for (int off = 32; off > 0; off >>= 1) {
            p0 += __shfl_xor(p0, off, 64);
            p1 += __shfl_xor(p1, off, 64);
        }

        const float s0 = p0 * LOG2E;
        const float s1 = p1 * LOG2E;
        const float gm = fmaxf(s0, s1);

        // Wave-uniform branch: rescale only when the running max increases
        if (gm > m) {
            const float scale = exp2f(m - gm);   // 2^(-inf) = 0 on first group
            lsum *= scale;
            #pragma unroll
            for (int q = 0; q < 4; ++q) {
                a[q].x *= scale;  a[q].y *= scale;
                a[q].z *= scale;  a[q].w *= scale;
            }
            m = gm;
        }

        const float w0 = exp2f(s0 - m);
        const float w1 = exp2f(s1 - m);
        lsum += w0 + w1;
        #pragma unroll
        for (int q = 0; q < 4; ++q) {
            a[q].x = fmaf(w1, R[buf][1][q].x, fmaf(w0, R[buf][0][q].x, a[q].x));
            a[q].y = fmaf(w1, R[buf][1][q].y, fmaf(w0, R[buf][0][q].y, a[q].y));
            a[q].z = fmaf(w1, R[buf][1][q].z, fmaf(w0, R[buf][0][q].z, a[q].z));
            a[q].w = fmaf(w1, R[buf][1][q].w, fmaf(w0, R[buf][0][q].w, a[q].w));
        }
    }

    // write partial record
    const size_t r = (size_t)b * SPLIT + k;
    float4* C = (float4*)(wsC + r * (size_t)HDIM);
    #pragma unroll
    for (int q = 0; q < 4; ++q) C[lane + 64 * q] = a[q];
    if (lane == 0) {
        wsML[2 * r]     = m;
        wsML[2 * r + 1] = lsum;
    }
}

// ---------------------------------------------------------------------------
// Kernel 2: combine split partials per batch, write context[b,h].
// Grid = BATCH*4 blocks; block (b, quarter) covers 256 h values (coalesced
// 1KB per record). m values are in base-2 domain.
// ---------------------------------------------------------------------------
__global__ __launch_bounds__(256) void attn_reduce_kernel(
    const float* __restrict__ wsC, const float* __restrict__ wsML,
    float* __restrict__ out, int split)
{
    const int b = blockIdx.x >> 2;
    const int q = blockIdx.x & 3;
    const int h = q * 256 + threadIdx.x;

    float M = -INFINITY;
    for (int k = 0; k < split; ++k)
        M = fmaxf(M, wsML[2 * ((size_t)b * split + k)]);

    float Ltot = 0.0f;
    float acc = 0.0f;
    for (int k = 0; k < split; ++k) {
        const size_t r = (size_t)b * split + k;
        const float wgt = exp2f(wsML[2 * r] - M);
        Ltot = fmaf(wsML[2 * r + 1], wgt, Ltot);
        acc = fmaf(wsC[r * (size_t)HDIM + h], wgt, acc);
    }
    out[(size_t)b * HDIM + h] = acc / Ltot;
}

extern "C" void kernel_launch(void* const* d_in, const int* in_sizes, int n_in,
                              void* d_out, int out_size, void* d_ws, size_t ws_size,
                              hipStream_t stream) {
    const float* enc = (const float*)d_in[0];   // [L, B, H] fp32
    const float* dec = (const float*)d_in[1];   // [1, B, H] fp32
    float* out = (float*)d_out;                 // [B, H] fp32

    // ws need for split s: B*s*H floats for wsC + B*s*2 for wsML.
    // ws_size is launch-invariant -> identical choice every call -> capture-safe.
    const size_t need128 = (size_t)BATCH * 128 * HDIM * sizeof(float)
                         + (size_t)BATCH * 128 * 2 * sizeof(float);
    float* wsC = (float*)d_ws;

    if (ws_size >= need128) {
        constexpr int SPLIT = 128, CHUNK = L_SEQ / 128;
        float* wsML = wsC + (size_t)BATCH * SPLIT * HDIM;
        attn_partial_kernel<SPLIT, CHUNK>
            <<<(BATCH * SPLIT) / WPB, 256, 0, stream>>>(enc, dec, wsC, wsML);
        attn_reduce_kernel<<<BATCH * 4, 256, 0, stream>>>(wsC, wsML, out, SPLIT);
    } else {
        constexpr int SPLIT = 16, CHUNK = L_SEQ / 16;   // 4.2 MB fallback
        float* wsML = wsC + (size_t)BATCH * SPLIT * HDIM;
        attn_partial_kernel<SPLIT, CHUNK>
            <<<(BATCH * SPLIT) / WPB, 256, 0, stream>>>(enc, dec, wsC, wsML);
        attn_reduce_kernel<<<BATCH * 4, 256, 0, stream>>>(wsC, wsML, out, SPLIT);
    }
}

// Round 4
// 379.288 us; speedup vs baseline: 1.0580x; 1.0580x over previous
//
#include <hip/hip_runtime.h>
#include <math.h>

// Problem constants (from reference setup_inputs)
#define L_SEQ 1024
#define BATCH 64
#define HDIM  1024
#define WPB   4      // waves per block (256 threads)

#define LOG2E 1.44269504088896340736f

// ---------------------------------------------------------------------------
// Kernel 1: per-(batch, l-chunk) online-softmax partials (flash-decode style).
// One wave per (b, chunk). Lane j owns h = {4j, 256+4j, 512+4j, 768+4j}
// (float4-strided: one wave load instruction = 64 lanes x 16B = 1KB contig).
// Light 2-deep ping-pong prefetch (only 8 float4 staging regs): next row's 4
// loads are issued before the current row's dot/butterfly/exp chain, keeping
// HBM requests in flight continuously. Rescale happens only when the running
// max increases (wave-uniform branch: post-butterfly scores are identical on
// all lanes). Softmax in base-2 domain (exp2f -> native v_exp_f32).
// Partial record r = b*SPLIT + k:
//   wsC[r*HDIM + h]      = sum_{l in chunk} 2^(s_l*log2e - m_r) * enc[l,b,h]
//   wsML[2r], wsML[2r+1] = (m_r, lsum_r)   (m in base-2 domain)
// ---------------------------------------------------------------------------
template <int SPLIT, int CHUNK>
__global__ __launch_bounds__(256) void attn_partial_kernel(
    const float* __restrict__ enc, const float* __restrict__ dec,
    float* __restrict__ wsC, float* __restrict__ wsML)
{
    const int tid  = threadIdx.x;
    const int lane = tid & 63;
    const int wave = tid >> 6;
    const int w    = blockIdx.x * WPB + wave;   // global wave id
    const int b    = w / SPLIT;
    const int k    = w - b * SPLIT;
    const int l0   = k * CHUNK;

    // This lane's slice of dec[b,:] (16 floats = 4 float4)
    const float4* decv = (const float4*)(dec + (size_t)b * HDIM);
    float4 d[4];
    #pragma unroll
    for (int q = 0; q < 4; ++q) d[q] = decv[lane + 64 * q];

    float m = -INFINITY;   // running max (base-2 domain)
    float lsum = 0.0f;
    float4 a[4];
    #pragma unroll
    for (int q = 0; q < 4; ++q) a[q] = make_float4(0.f, 0.f, 0.f, 0.f);

    const size_t row_stride = (size_t)BATCH * HDIM;  // floats from l to l+1
    const float* base0 = enc + ((size_t)l0 * BATCH + b) * HDIM;

    // Process one row from buffer `e` (dot -> butterfly -> online softmax).
    float4 B0[4], B1[4];
    auto process = [&](const float4* e) {
        float p = 0.0f;
        #pragma unroll
        for (int q = 0; q < 4; ++q) {
            p = fmaf(e[q].x, d[q].x, p);
            p = fmaf(e[q].y, d[q].y, p);
            p = fmaf(e[q].z, d[q].z, p);
            p = fmaf(e[q].w, d[q].w, p);
        }
        #pragma unroll
        for (int off = 32; off > 0; off >>= 1)
            p += __shfl_xor(p, off, 64);

        const float s = p * LOG2E;
        if (s > m) {                       // wave-uniform; rare after warmup
            const float scale = exp2f(m - s);   // 2^(-inf) = 0 on first row
            lsum *= scale;
            #pragma unroll
            for (int q = 0; q < 4; ++q) {
                a[q].x *= scale;  a[q].y *= scale;
                a[q].z *= scale;  a[q].w *= scale;
            }
            m = s;
        }
        const float wgt = exp2f(s - m);
        lsum += wgt;
        #pragma unroll
        for (int q = 0; q < 4; ++q) {
            a[q].x = fmaf(wgt, e[q].x, a[q].x);
            a[q].y = fmaf(wgt, e[q].y, a[q].y);
            a[q].z = fmaf(wgt, e[q].z, a[q].z);
            a[q].w = fmaf(wgt, e[q].w, a[q].w);
        }
    };

    // Prime buffer 0 with row l0
    {
        const float4* row = (const float4*)base0;
        #pragma unroll
        for (int q = 0; q < 4; ++q) B0[q] = row[lane + 64 * q];
    }

    #pragma unroll
    for (int g = 0; g < CHUNK; g += 2) {
        // Prefetch row g+1 into B1, then process row g from B0
        {
            const float4* row = (const float4*)(base0 + (size_t)(g + 1) * row_stride);
            #pragma unroll
            for (int q = 0; q < 4; ++q) B1[q] = row[lane + 64 * q];
        }
        process(B0);
        // Prefetch row g+2 into B0, then process row g+1 from B1
        if (g + 2 < CHUNK) {
            const float4* row = (const float4*)(base0 + (size_t)(g + 2) * row_stride);
            #pragma unroll
            for (int q = 0; q < 4; ++q) B0[q] = row[lane + 64 * q];
        }
        process(B1);
    }

    // write partial record
    const size_t r = (size_t)b * SPLIT + k;
    float4* C = (float4*)(wsC + r * (size_t)HDIM);
    #pragma unroll
    for (int q = 0; q < 4; ++q) C[lane + 64 * q] = a[q];
    if (lane == 0) {
        wsML[2 * r]     = m;
        wsML[2 * r + 1] = lsum;
    }
}

// ---------------------------------------------------------------------------
// Kernel 2: combine split partials per batch, write context[b,h].
// Grid = BATCH*4 blocks; block (b, quarter) covers 256 h values (coalesced
// 1KB per record). m values are in base-2 domain.
// ---------------------------------------------------------------------------
__global__ __launch_bounds__(256) void attn_reduce_kernel(
    const float* __restrict__ wsC, const float* __restrict__ wsML,
    float* __restrict__ out, int split)
{
    const int b = blockIdx.x >> 2;
    const int q = blockIdx.x & 3;
    const int h = q * 256 + threadIdx.x;

    float M = -INFINITY;
    for (int k = 0; k < split; ++k)
        M = fmaxf(M, wsML[2 * ((size_t)b * split + k)]);

    float Ltot = 0.0f;
    float acc = 0.0f;
    for (int k = 0; k < split; ++k) {
        const size_t r = (size_t)b * split + k;
        const float wgt = exp2f(wsML[2 * r] - M);
        Ltot = fmaf(wsML[2 * r + 1], wgt, Ltot);
        acc = fmaf(wsC[r * (size_t)HDIM + h], wgt, acc);
    }
    out[(size_t)b * HDIM + h] = acc / Ltot;
}

extern "C" void kernel_launch(void* const* d_in, const int* in_sizes, int n_in,
                              void* d_out, int out_size, void* d_ws, size_t ws_size,
                              hipStream_t stream) {
    const float* enc = (const float*)d_in[0];   // [L, B, H] fp32
    const float* dec = (const float*)d_in[1];   // [1, B, H] fp32
    float* out = (float*)d_out;                 // [B, H] fp32

    // ws need for split s: B*s*H floats for wsC + B*s*2 for wsML.
    // ws_size is launch-invariant -> identical choice every call -> capture-safe.
    const size_t need64 = (size_t)BATCH * 64 * HDIM * sizeof(float)
                        + (size_t)BATCH * 64 * 2 * sizeof(float);
    float* wsC = (float*)d_ws;

    if (ws_size >= need64) {
        constexpr int SPLIT = 64, CHUNK = L_SEQ / 64;
        float* wsML = wsC + (size_t)BATCH * SPLIT * HDIM;
        attn_partial_kernel<SPLIT, CHUNK>
            <<<(BATCH * SPLIT) / WPB, 256, 0, stream>>>(enc, dec, wsC, wsML);
        attn_reduce_kernel<<<BATCH * 4, 256, 0, stream>>>(wsC, wsML, out, SPLIT);
    } else {
        constexpr int SPLIT = 8, CHUNK = L_SEQ / 8;   // 2.1 MB fallback
        float* wsML = wsC + (size_t)BATCH * SPLIT * HDIM;
        attn_partial_kernel<SPLIT, CHUNK>
            <<<(BATCH * SPLIT) / WPB, 256, 0, stream>>>(enc, dec, wsC, wsML);
        attn_reduce_kernel<<<BATCH * 4, 256, 0, stream>>>(wsC, wsML, out, SPLIT);
    }
}

// Round 5
// 370.391 us; speedup vs baseline: 1.0834x; 1.0240x over previous
//
#include <hip/hip_runtime.h>
#include <math.h>

// Problem constants (from reference setup_inputs)
#define L_SEQ 1024
#define BATCH 64
#define HDIM  1024
#define WPB   4      // waves per block (256 threads)

#define LOG2E 1.44269504088896340736f

// ---------------------------------------------------------------------------
// Kernel 1: per-(batch, l-chunk) online-softmax partials (flash-decode style).
// One wave per (b, chunk). Lane j owns h = {4j, 256+4j, 512+4j, 768+4j}
// (float4-strided: one wave load instruction = 64 lanes x 16B = 1KB contig).
// Skinny body (~80 VGPR -> ~24 waves/CU at SPLIT=128) with 2-deep ping-pong
// prefetch so 8KB/wave stays in flight through the dot/butterfly/exp chain.
// Rescale only when the running max increases (wave-uniform branch).
// Softmax in base-2 domain (exp2f -> native v_exp_f32).
// Partial record r = b*SPLIT + k:
//   wsC[r*HDIM + h]      = sum_{l in chunk} 2^(s_l*log2e - m_r) * enc[l,b,h]
//   wsML[2r], wsML[2r+1] = (m_r, lsum_r)   (m in base-2 domain)
// ---------------------------------------------------------------------------
template <int SPLIT, int CHUNK>
__global__ __launch_bounds__(256) void attn_partial_kernel(
    const float* __restrict__ enc, const float* __restrict__ dec,
    float* __restrict__ wsC, float* __restrict__ wsML)
{
    const int tid  = threadIdx.x;
    const int lane = tid & 63;
    const int wave = tid >> 6;
    const int w    = blockIdx.x * WPB + wave;   // global wave id
    const int b    = w / SPLIT;
    const int k    = w - b * SPLIT;
    const int l0   = k * CHUNK;

    // This lane's slice of dec[b,:] (16 floats = 4 float4)
    const float4* decv = (const float4*)(dec + (size_t)b * HDIM);
    float4 d[4];
    #pragma unroll
    for (int q = 0; q < 4; ++q) d[q] = decv[lane + 64 * q];

    float m = -INFINITY;   // running max (base-2 domain)
    float lsum = 0.0f;
    float4 a[4];
    #pragma unroll
    for (int q = 0; q < 4; ++q) a[q] = make_float4(0.f, 0.f, 0.f, 0.f);

    const size_t row_stride = (size_t)BATCH * HDIM;  // floats from l to l+1
    const float* base0 = enc + ((size_t)l0 * BATCH + b) * HDIM;

    float4 B0[4], B1[4];
    auto process = [&](const float4* e) {
        float p = 0.0f;
        #pragma unroll
        for (int q = 0; q < 4; ++q) {
            p = fmaf(e[q].x, d[q].x, p);
            p = fmaf(e[q].y, d[q].y, p);
            p = fmaf(e[q].z, d[q].z, p);
            p = fmaf(e[q].w, d[q].w, p);
        }
        #pragma unroll
        for (int off = 32; off > 0; off >>= 1)
            p += __shfl_xor(p, off, 64);

        const float s = p * LOG2E;
        if (s > m) {                       // wave-uniform; rare after warmup
            const float scale = exp2f(m - s);   // 2^(-inf) = 0 on first row
            lsum *= scale;
            #pragma unroll
            for (int q = 0; q < 4; ++q) {
                a[q].x *= scale;  a[q].y *= scale;
                a[q].z *= scale;  a[q].w *= scale;
            }
            m = s;
        }
        const float wgt = exp2f(s - m);
        lsum += wgt;
        #pragma unroll
        for (int q = 0; q < 4; ++q) {
            a[q].x = fmaf(wgt, e[q].x, a[q].x);
            a[q].y = fmaf(wgt, e[q].y, a[q].y);
            a[q].z = fmaf(wgt, e[q].z, a[q].z);
            a[q].w = fmaf(wgt, e[q].w, a[q].w);
        }
    };

    // Prime buffer 0 with row l0
    {
        const float4* row = (const float4*)base0;
        #pragma unroll
        for (int q = 0; q < 4; ++q) B0[q] = row[lane + 64 * q];
    }

    #pragma unroll
    for (int g = 0; g < CHUNK; g += 2) {
        // Prefetch row g+1 into B1, then process row g from B0
        {
            const float4* row = (const float4*)(base0 + (size_t)(g + 1) * row_stride);
            #pragma unroll
            for (int q = 0; q < 4; ++q) B1[q] = row[lane + 64 * q];
        }
        process(B0);
        // Prefetch row g+2 into B0, then process row g+1 from B1
        if (g + 2 < CHUNK) {
            const float4* row = (const float4*)(base0 + (size_t)(g + 2) * row_stride);
            #pragma unroll
            for (int q = 0; q < 4; ++q) B0[q] = row[lane + 64 * q];
        }
        process(B1);
    }

    // write partial record
    const size_t r = (size_t)b * SPLIT + k;
    float4* C = (float4*)(wsC + r * (size_t)HDIM);
    #pragma unroll
    for (int q = 0; q < 4; ++q) C[lane + 64 * q] = a[q];
    if (lane == 0) {
        wsML[2 * r]     = m;
        wsML[2 * r + 1] = lsum;
    }
}

// ---------------------------------------------------------------------------
// Kernel 2: combine split partials per batch, write context[b,h].
// Grid = BATCH*4 blocks = (b, h-quarter); 4 waves per block, wave wv owns
// k in {wv, wv+4, wv+8, ...} with a WAVE-LOCAL max (no pre-loop barrier),
// unrolled x4 for load ILP. One LDS combine at the end rescales the four
// wave partials to the global max. m values are in base-2 domain.
// ---------------------------------------------------------------------------
template <int SPLIT>
__global__ __launch_bounds__(256) void attn_reduce_kernel(
    const float* __restrict__ wsC, const float* __restrict__ wsML,
    float* __restrict__ out)
{
    constexpr int KPW = SPLIT / 4;       // k values per wave
    const int b  = blockIdx.x >> 2;
    const int hq = blockIdx.x & 3;
    const int wv = threadIdx.x >> 6;
    const int ln = threadIdx.x & 63;
    const int h4 = hq * 64 + ln;         // float4 index into the H row

    // Wave-local max over this wave's k slice (scalar broadcast loads)
    float mw = -INFINITY;
    #pragma unroll 4
    for (int i = 0; i < KPW; ++i) {
        const int r = b * SPLIT + wv + 4 * i;
        mw = fmaxf(mw, wsML[2 * r]);
    }

    // Accumulate this wave's slice against the wave-local max
    float lt = 0.0f;
    float4 acc = make_float4(0.f, 0.f, 0.f, 0.f);
    #pragma unroll 4
    for (int i = 0; i < KPW; ++i) {
        const int r = b * SPLIT + wv + 4 * i;
        const float wgt = exp2f(wsML[2 * r] - mw);
        lt = fmaf(wsML[2 * r + 1], wgt, lt);
        const float4 c = ((const float4*)(wsC + (size_t)r * HDIM))[h4];
        acc.x = fmaf(wgt, c.x, acc.x);
        acc.y = fmaf(wgt, c.y, acc.y);
        acc.z = fmaf(wgt, c.z, acc.z);
        acc.w = fmaf(wgt, c.w, acc.w);
    }

    __shared__ float4 lacc[4][64];
    __shared__ float  lml[4][2];
    lacc[wv][ln] = acc;
    if (ln == 0) { lml[wv][0] = mw; lml[wv][1] = lt; }
    __syncthreads();

    if (wv == 0) {
        const float M = fmaxf(fmaxf(lml[0][0], lml[1][0]),
                              fmaxf(lml[2][0], lml[3][0]));
        const float w0 = exp2f(lml[0][0] - M);
        const float w1 = exp2f(lml[1][0] - M);
        const float w2 = exp2f(lml[2][0] - M);
        const float w3 = exp2f(lml[3][0] - M);
        const float Lt = lml[0][1] * w0 + lml[1][1] * w1
                       + lml[2][1] * w2 + lml[3][1] * w3;
        const float inv = 1.0f / Lt;
        const float4 a0 = lacc[0][ln], a1 = lacc[1][ln];
        const float4 a2 = lacc[2][ln], a3 = lacc[3][ln];
        float4 o;
        o.x = (a0.x * w0 + a1.x * w1 + a2.x * w2 + a3.x * w3) * inv;
        o.y = (a0.y * w0 + a1.y * w1 + a2.y * w2 + a3.y * w3) * inv;
        o.z = (a0.z * w0 + a1.z * w1 + a2.z * w2 + a3.z * w3) * inv;
        o.w = (a0.w * w0 + a1.w * w1 + a2.w * w2 + a3.w * w3) * inv;
        ((float4*)(out + (size_t)b * HDIM))[h4] = o;
    }
}

extern "C" void kernel_launch(void* const* d_in, const int* in_sizes, int n_in,
                              void* d_out, int out_size, void* d_ws, size_t ws_size,
                              hipStream_t stream) {
    const float* enc = (const float*)d_in[0];   // [L, B, H] fp32
    const float* dec = (const float*)d_in[1];   // [1, B, H] fp32
    float* out = (float*)d_out;                 // [B, H] fp32

    // ws need for split s: B*s*H floats for wsC + B*s*2 for wsML.
    // ws_size is launch-invariant -> identical choice every call -> capture-safe.
    const size_t need128 = (size_t)BATCH * 128 * HDIM * sizeof(float)
                         + (size_t)BATCH * 128 * 2 * sizeof(float);
    float* wsC = (float*)d_ws;

    if (ws_size >= need128) {
        constexpr int SPLIT = 128, CHUNK = L_SEQ / 128;
        float* wsML = wsC + (size_t)BATCH * SPLIT * HDIM;
        attn_partial_kernel<SPLIT, CHUNK>
            <<<(BATCH * SPLIT) / WPB, 256, 0, stream>>>(enc, dec, wsC, wsML);
        attn_reduce_kernel<SPLIT><<<BATCH * 4, 256, 0, stream>>>(wsC, wsML, out);
    } else {
        constexpr int SPLIT = 8, CHUNK = L_SEQ / 8;   // 2.1 MB fallback
        float* wsML = wsC + (size_t)BATCH * SPLIT * HDIM;
        attn_partial_kernel<SPLIT, CHUNK>
            <<<(BATCH * SPLIT) / WPB, 256, 0, stream>>>(enc, dec, wsC, wsML);
        attn_reduce_kernel<SPLIT><<<BATCH * 4, 256, 0, stream>>>(wsC, wsML, out);
    }
}